// Round 6
// baseline (319.313 us; speedup 1.0000x reference)
//
#include <hip/hip_runtime.h>
#include <stdint.h>

typedef unsigned short u16;
typedef unsigned int   u32;
typedef __bf16 bf16_t;
typedef bf16_t bf16x8 __attribute__((ext_vector_type(8)));
typedef bf16_t bf16x2 __attribute__((ext_vector_type(2)));
typedef float  f32x2  __attribute__((ext_vector_type(2)));
typedef float  f32x4  __attribute__((ext_vector_type(4)));

// bs=8, H=8 -> bH=64 ; T=1024 ; ch=64 ; classes 0..7, null token idx 8.
// Math: k-bias is row-constant over surviving keys -> drops out of softmax;
// v-bias passes through softmax as exactly +v_bias -> added in epilogue;
// counter==2 -> out = 0.5*(A_null + A_class).  No-max softmax: logits in
// exp2-domain have sigma~1.44 (scale folded into Q), so raw exp2 is safe.
#define QSCALE 0.18033688011112042f   /* 0.125 * log2(e) */
#define LP 72                          /* LDS pitch (elems) for ktr/vls/P */

__device__ __forceinline__ u32 pkbf(float a, float b) {
  f32x2 x = {a, b};
  bf16x2 y = __builtin_convertvector(x, bf16x2);   // RNE; v_cvt_pk_bf16_f32
  union { bf16x2 v; u32 u; } c; c.v = y; return c.u;
}

// raw v_exp_f32: libm exp2f (no fast-math) lowers to a denormal-fixup
// expansion; the raw instruction is exact for our range.
__device__ __forceinline__ float fexp2(float x) {
#if __has_builtin(__builtin_amdgcn_exp2f)
  return __builtin_amdgcn_exp2f(x);
#else
  float r;
  asm("v_exp_f32 %0, %1\n\ts_nop 0" : "=v"(r) : "v"(x));
  return r;
#endif
}

// ---- kernel 1: tok[c][j] = sum_i W_cls[j,i] * embed[c,i]  (9 x 192) --------
__global__ void tok_kernel(const float* __restrict__ W, const float* __restrict__ E,
                           float* __restrict__ tok) {
  int c = blockIdx.x;           // 0..8
  int j = threadIdx.x;          // 0..191
  const f32x4* wr = (const f32x4*)(W + j * 512);
  const f32x4* er = (const f32x4*)(E + c * 512);
  float acc = 0.f;
  for (int i = 0; i < 128; ++i) {
    f32x4 w = wr[i], e = er[i];
    acc += w.x * e.x + w.y * e.y + w.z * e.z + w.w * e.w;
  }
  tok[c * 192 + j] = acc;
}

// ---- kernel 2: two-stream flash attention ----------------------------------
// waves_per_eu pinned to exactly 4: with [4,8] the backend targets 8 waves/EU
// (64 VGPR) and spills the prefetch arrays to scratch (R5: WRITE_SIZE 429 MB,
// 2.2x regression).  4 waves/EU -> 128-VGPR budget, prefetch stays in regs.
__global__ __launch_bounds__(256)
__attribute__((amdgpu_waves_per_eu(4, 4)))
void attn_kernel(const float* __restrict__ qkv, const int* __restrict__ seg,
                 const float* __restrict__ tok, float* __restrict__ out) {
  // ktr [64 s][LP] (K transposed, columns XOR-swizzled) | vls [64 d][LP]
  // (V, key order permuted: col' = (s&15)*4 + (s>>4)) | P per wave [2][16][LP]
  __shared__ __align__(16) u16 smem[64 * LP * 2 + 4 * 2 * 16 * LP];  // 36864 B
  u16* ktr = smem;
  u16* vls = smem + 64 * LP;

  const int bh = blockIdx.x, qt = blockIdx.y, b = bh >> 3;
  const int tid = threadIdx.x, wave = tid >> 6, lane = tid & 63;
  const int quad = lane >> 4, l16 = lane & 15;
  u16* Pw = smem + 2 * 64 * LP + wave * (2 * 16 * LP);

  const float* qg   = qkv + (size_t)bh * 192 * 1024;   // head slab [192][1024]
  const int*   segb = seg + b * 1024;

  // --- per-lane segment info -------------------------------------------------
  const int tq = qt * 64 + wave * 16 + l16;
  const int mycls = segb[tq];
  int sq[4];
#pragma unroll
  for (int r = 0; r < 4; ++r) sq[r] = segb[qt * 64 + wave * 16 + quad * 4 + r];

  // --- Q fragments (A-layout: m=l16=query, k=d=kc*32+quad*8+j) --------------
  const float* tn = tok + 8 * 192;
  const float* tc = tok + mycls * 192;
  union { u32 w[4]; bf16x8 v; } q0f[2], qbf[2];
#pragma unroll
  for (int kc = 0; kc < 2; ++kc)
#pragma unroll
    for (int jj = 0; jj < 4; ++jj) {
      int d = kc * 32 + quad * 8 + jj * 2;
      float a0 = qg[(size_t)d * 1024 + tq];
      float a1 = qg[(size_t)(d + 1) * 1024 + tq];
      q0f[kc].w[jj] = pkbf((a0 + tn[d]) * QSCALE, (a1 + tn[d + 1]) * QSCALE);
      qbf[kc].w[jj] = pkbf((a0 + tc[d]) * QSCALE, (a1 + tc[d + 1]) * QSCALE);
    }

  f32x4 O0[4], Ob[4];
#pragma unroll
  for (int dt = 0; dt < 4; ++dt) {
    O0[dt] = (f32x4){0.f, 0.f, 0.f, 0.f};
    Ob[dt] = (f32x4){0.f, 0.f, 0.f, 0.f};
  }
  float rs0[4] = {0.f, 0.f, 0.f, 0.f}, rsb[4] = {0.f, 0.f, 0.f, 0.f};

  // --- staging thread constants ---------------------------------------------
  const int c4 = tid & 15, row0 = tid >> 4;            // float4 col, d-row base
  const f32x4* kg4 = (const f32x4*)(qg + 64 * 1024);
  const f32x4* vg4 = (const f32x4*)(qg + 128 * 1024);
  const int vpb   = 16 * (c4 & 3) + (c4 >> 2);         // perm(4*c4+i) = vpb+4i
  const int kswz  = (c4 & 7) << 3;                     // ktr column XOR swizzle

  // --- software pipeline: tile kt+1's global loads fly during tile kt -------
  f32x4 kpre[4], vpre[4];
  int skpre[4];
#pragma unroll
  for (int r2 = 0; r2 < 4; ++r2) {
    const int dl = r2 * 16 + row0;
    kpre[r2] = kg4[dl * 256 + c4];
    vpre[r2] = vg4[dl * 256 + c4];
  }
#pragma unroll
  for (int n4 = 0; n4 < 4; ++n4) skpre[n4] = segb[n4 * 16 + l16];

  // ---- key-tile loop (16 x 64 keys) ----------------------------------------
  for (int kt = 0; kt < 16; ++kt) {
    __syncthreads();                     // prior tile's LDS reads complete

    // stage K (transposed+swizzled) and V (permuted cols) from prefetch regs
#pragma unroll
    for (int r2 = 0; r2 < 4; ++r2) {
      const int dl = r2 * 16 + row0;
      f32x4 kv = kpre[r2], vv = vpre[r2];
      u32 k01 = pkbf(kv.x, kv.y), k23 = pkbf(kv.z, kv.w);
      u32 v01 = pkbf(vv.x, vv.y), v23 = pkbf(vv.z, vv.w);
      u16* kb = &ktr[(4 * c4) * LP + (dl ^ kswz)];
      kb[0]      = (u16)k01;
      kb[LP]     = (u16)(k01 >> 16);
      kb[2 * LP] = (u16)k23;
      kb[3 * LP] = (u16)(k23 >> 16);
      u16* vb = &vls[dl * LP + vpb];
      vb[0]  = (u16)v01;
      vb[4]  = (u16)(v01 >> 16);
      vb[8]  = (u16)v23;
      vb[12] = (u16)(v23 >> 16);
    }
    int sk[4];
#pragma unroll
    for (int n4 = 0; n4 < 4; ++n4) sk[n4] = skpre[n4];
    __syncthreads();                     // staging visible

    if (kt < 15) {                       // issue next tile's loads now
      const int koff = (kt + 1) * 16 + c4;
#pragma unroll
      for (int r2 = 0; r2 < 4; ++r2) {
        const int dl = r2 * 16 + row0;
        kpre[r2] = kg4[dl * 256 + koff];
        vpre[r2] = vg4[dl * 256 + koff];
      }
      const int s1 = (kt + 1) * 64;
#pragma unroll
      for (int n4 = 0; n4 < 4; ++n4) skpre[n4] = segb[s1 + n4 * 16 + l16];
    }

    // ---- S = Q K^T, both streams (B-frag: n=key=n4*16+l16, k=d) -----------
    f32x4 S0[4], Sb[4];
#pragma unroll
    for (int n4 = 0; n4 < 4; ++n4) {
      const int scol = n4 * 16 + l16;
      const int h8   = ((scol >> 2) & 7) << 3;         // read-side unswizzle
      f32x4 a0 = {0.f, 0.f, 0.f, 0.f}, ab = {0.f, 0.f, 0.f, 0.f};
#pragma unroll
      for (int kc = 0; kc < 2; ++kc) {
        bf16x8 kf = *(const bf16x8*)&ktr[scol * LP + ((kc * 32 + quad * 8) ^ h8)];
        a0 = __builtin_amdgcn_mfma_f32_16x16x32_bf16(q0f[kc].v, kf, a0, 0, 0, 0);
        ab = __builtin_amdgcn_mfma_f32_16x16x32_bf16(qbf[kc].v, kf, ab, 0, 0, 0);
      }
      S0[n4] = a0; Sb[n4] = ab;
    }

    // ---- no-max softmax: raw exp2, per-lane partial row sums --------------
#pragma unroll
    for (int r = 0; r < 4; ++r) {
      float p0[4], pb[4];
#pragma unroll
      for (int n4 = 0; n4 < 4; ++n4) {
        p0[n4] = fexp2(S0[n4][r]);
        pb[n4] = (sk[n4] == sq[r]) ? fexp2(Sb[n4][r]) : 0.f;
      }
      rs0[r] += (p0[0] + p0[1]) + (p0[2] + p0[3]);
      rsb[r] += (pb[0] + pb[1]) + (pb[2] + pb[3]);
      // P at col' = l16*4 + n4  (matches V's perm)  -> one b64 per stream
      *(uint2*)&Pw[(quad * 4 + r) * LP + l16 * 4] =
          make_uint2(pkbf(p0[0], p0[1]), pkbf(p0[2], p0[3]));
      *(uint2*)&Pw[16 * LP + (quad * 4 + r) * LP + l16 * 4] =
          make_uint2(pkbf(pb[0], pb[1]), pkbf(pb[2], pb[3]));
    }
    asm volatile("s_waitcnt lgkmcnt(0)" ::: "memory");  // wave-private P RAW

    // ---- O += P V  (A=P[m=q][k=col'], B=V[k=col'][n=d]) -------------------
#pragma unroll
    for (int kc = 0; kc < 2; ++kc) {
      bf16x8 pf0 = *(const bf16x8*)&Pw[l16 * LP + kc * 32 + quad * 8];
      bf16x8 pfb = *(const bf16x8*)&Pw[16 * LP + l16 * LP + kc * 32 + quad * 8];
#pragma unroll
      for (int dt = 0; dt < 4; ++dt) {
        bf16x8 vf = *(const bf16x8*)&vls[(dt * 16 + l16) * LP + kc * 32 + quad * 8];
        O0[dt] = __builtin_amdgcn_mfma_f32_16x16x32_bf16(pf0, vf, O0[dt], 0, 0, 0);
        Ob[dt] = __builtin_amdgcn_mfma_f32_16x16x32_bf16(pfb, vf, Ob[dt], 0, 0, 0);
      }
    }
  }

  // ---- final row-sum reduction (within 16-lane row groups) -----------------
#pragma unroll
  for (int r = 0; r < 4; ++r)
#pragma unroll
    for (int off = 1; off < 16; off <<= 1) {
      rs0[r] += __shfl_xor(rs0[r], off, 64);
      rsb[r] += __shfl_xor(rsb[r], off, 64);
    }
  float inv0[4], invb[4];
#pragma unroll
  for (int r = 0; r < 4; ++r) {
    inv0[r] = (rs0[r] > 0.f) ? 1.f / rs0[r] : 0.f;
    invb[r] = (rsb[r] > 0.f) ? 1.f / rsb[r] : 0.f;
  }

  // ---- epilogue: divide, add analytic v-biases, transpose via LDS, store ---
  __syncthreads();                        // all LDS tile reads done
  float* fbuf = (float*)smem;             // [64 d][65] fp32
  const float* tvn = tok + 8 * 192 + 128;
#pragma unroll
  for (int dt = 0; dt < 4; ++dt) {
    const int d = dt * 16 + l16;
    const float bn = tvn[d];
#pragma unroll
    for (int r = 0; r < 4; ++r) {
      float bc = tok[sq[r] * 192 + 128 + d];
      float vA = O0[dt][r] * inv0[r] + bn;
      float vB = Ob[dt][r] * invb[r] + bc;
      fbuf[d * 65 + wave * 16 + quad * 4 + r] = 0.5f * (vA + vB);
    }
  }
  __syncthreads();
  {
    // out flat = d*65536 + bh*1024 + t   (stacked (ch, bH, T) row-major)
    const size_t obase = (size_t)bh * 1024 + qt * 64;
    for (int i = tid; i < 4096; i += 256) {
      int d = i >> 6, t = i & 63;
      out[(size_t)d * 65536 + obase + t] = fbuf[d * 65 + t];
    }
  }
}

// ---- host ------------------------------------------------------------------
extern "C" void kernel_launch(void* const* d_in, const int* in_sizes, int n_in,
                              void* d_out, int out_size, void* d_ws, size_t ws_size,
                              hipStream_t stream) {
  (void)in_sizes; (void)n_in; (void)out_size; (void)ws_size;
  const float* qkv   = (const float*)d_in[0];
  const int*   amask = (const int*)d_in[1];
  const float* emb   = (const float*)d_in[2];
  const float* wcls  = (const float*)d_in[3];
  float* tok = (float*)d_ws;
  float* out = (float*)d_out;

  hipLaunchKernelGGL(tok_kernel, dim3(9), dim3(192), 0, stream, wcls, emb, tok);
  hipLaunchKernelGGL(attn_kernel, dim3(64, 16), dim3(256), 0, stream,
                     qkv, amask, tok, out);
}

// Round 7
// 177.583 us; speedup vs baseline: 1.7981x; 1.7981x over previous
//
#include <hip/hip_runtime.h>
#include <stdint.h>

typedef unsigned short u16;
typedef unsigned int   u32;
typedef __bf16 bf16_t;
typedef bf16_t bf16x8 __attribute__((ext_vector_type(8)));
typedef bf16_t bf16x2 __attribute__((ext_vector_type(2)));
typedef float  f32x2  __attribute__((ext_vector_type(2)));
typedef float  f32x4  __attribute__((ext_vector_type(4)));

// bs=8, H=8 -> bH=64 ; T=1024 ; ch=64 ; classes 0..7, null token idx 8.
// Math: k-bias is row-constant over surviving keys -> drops out of softmax;
// v-bias passes through softmax as exactly +v_bias -> added in epilogue;
// counter==2 -> out = 0.5*(A_null + A_class).  No-max softmax: logits in
// exp2-domain have sigma~1.44 (scale folded into Q), so raw exp2 is safe.
//
// NOTE (R5/R6 lesson): any register prefetch beyond the 64-VGPR allocation
// this kernel gets SPILLS TO SCRATCH (429 MB writes/dispatch, 2.2x slower);
// amdgpu_waves_per_eu(4,4) did NOT lift the budget.  Structure below is the
// proven R4 shape (64 VGPR, zero spill) + raw v_exp_f32 softmax.
#define QSCALE 0.18033688011112042f   /* 0.125 * log2(e) */
#define LP 72                          /* LDS pitch (elems) for ktr/vls/P */

__device__ __forceinline__ u32 pkbf(float a, float b) {
  f32x2 x = {a, b};
  bf16x2 y = __builtin_convertvector(x, bf16x2);   // RNE; v_cvt_pk_bf16_f32
  union { bf16x2 v; u32 u; } c; c.v = y; return c.u;
}

// raw v_exp_f32: libm exp2f (no fast-math) lowers to a multi-instruction
// denormal-fixup expansion; raw instruction is exact for our exponent range.
__device__ __forceinline__ float fexp2(float x) {
#if __has_builtin(__builtin_amdgcn_exp2f)
  return __builtin_amdgcn_exp2f(x);
#else
  float r;
  asm("v_exp_f32 %0, %1\n\ts_nop 0" : "=v"(r) : "v"(x));
  return r;
#endif
}

// ---- kernel 1: tok[c][j] = sum_i W_cls[j,i] * embed[c,i]  (9 x 192) --------
__global__ void tok_kernel(const float* __restrict__ W, const float* __restrict__ E,
                           float* __restrict__ tok) {
  int c = blockIdx.x;           // 0..8
  int j = threadIdx.x;          // 0..191
  const f32x4* wr = (const f32x4*)(W + j * 512);
  const f32x4* er = (const f32x4*)(E + c * 512);
  float acc = 0.f;
  for (int i = 0; i < 128; ++i) {
    f32x4 w = wr[i], e = er[i];
    acc += w.x * e.x + w.y * e.y + w.z * e.z + w.w * e.w;
  }
  tok[c * 192 + j] = acc;
}

// ---- kernel 2: two-stream flash attention ----------------------------------
__global__ __launch_bounds__(256, 4)
void attn_kernel(const float* __restrict__ qkv, const int* __restrict__ seg,
                 const float* __restrict__ tok, float* __restrict__ out) {
  // ktr [64 s][LP] (K transposed, columns XOR-swizzled) | vls [64 d][LP]
  // (V, key order permuted: col' = (s&15)*4 + (s>>4)) | P per wave [2][16][LP]
  __shared__ __align__(16) u16 smem[64 * LP * 2 + 4 * 2 * 16 * LP];  // 36864 B
  u16* ktr = smem;
  u16* vls = smem + 64 * LP;

  const int bh = blockIdx.x, qt = blockIdx.y, b = bh >> 3;
  const int tid = threadIdx.x, wave = tid >> 6, lane = tid & 63;
  const int quad = lane >> 4, l16 = lane & 15;
  u16* Pw = smem + 2 * 64 * LP + wave * (2 * 16 * LP);

  const float* qg   = qkv + (size_t)bh * 192 * 1024;   // head slab [192][1024]
  const int*   segb = seg + b * 1024;

  // --- per-lane segment info -------------------------------------------------
  const int tq = qt * 64 + wave * 16 + l16;
  const int mycls = segb[tq];
  int sq[4];
#pragma unroll
  for (int r = 0; r < 4; ++r) sq[r] = segb[qt * 64 + wave * 16 + quad * 4 + r];

  // --- Q fragments (A-layout: m=l16=query, k=d=kc*32+quad*8+j) --------------
  const float* tn = tok + 8 * 192;
  const float* tc = tok + mycls * 192;
  union { u32 w[4]; bf16x8 v; } q0f[2], qbf[2];
#pragma unroll
  for (int kc = 0; kc < 2; ++kc)
#pragma unroll
    for (int jj = 0; jj < 4; ++jj) {
      int d = kc * 32 + quad * 8 + jj * 2;
      float a0 = qg[(size_t)d * 1024 + tq];
      float a1 = qg[(size_t)(d + 1) * 1024 + tq];
      q0f[kc].w[jj] = pkbf((a0 + tn[d]) * QSCALE, (a1 + tn[d + 1]) * QSCALE);
      qbf[kc].w[jj] = pkbf((a0 + tc[d]) * QSCALE, (a1 + tc[d + 1]) * QSCALE);
    }

  f32x4 O0[4], Ob[4];
#pragma unroll
  for (int dt = 0; dt < 4; ++dt) {
    O0[dt] = (f32x4){0.f, 0.f, 0.f, 0.f};
    Ob[dt] = (f32x4){0.f, 0.f, 0.f, 0.f};
  }
  float rs0[4] = {0.f, 0.f, 0.f, 0.f}, rsb[4] = {0.f, 0.f, 0.f, 0.f};

  // --- staging thread constants ---------------------------------------------
  const int c4 = tid & 15, row0 = tid >> 4;            // float4 col, d-row base
  const f32x4* kg4 = (const f32x4*)(qg + 64 * 1024);
  const f32x4* vg4 = (const f32x4*)(qg + 128 * 1024);
  const int vpb   = 16 * (c4 & 3) + (c4 >> 2);         // perm(4*c4+i) = vpb+4i
  const int kswz  = (c4 & 7) << 3;                     // ktr column XOR swizzle

  // ---- key-tile loop (16 x 64 keys) ----------------------------------------
  for (int kt = 0; kt < 16; ++kt) {
    const int s0 = kt * 64;
    __syncthreads();                     // prior tile's LDS reads complete

    // stage K (transposed+swizzled) and V (permuted cols) -------------------
#pragma unroll
    for (int r2 = 0; r2 < 4; ++r2) {
      const int dl = r2 * 16 + row0;
      f32x4 kv = kg4[dl * 256 + kt * 16 + c4];
      f32x4 vv = vg4[dl * 256 + kt * 16 + c4];
      u32 k01 = pkbf(kv.x, kv.y), k23 = pkbf(kv.z, kv.w);
      u32 v01 = pkbf(vv.x, vv.y), v23 = pkbf(vv.z, vv.w);
      u16* kb = &ktr[(4 * c4) * LP + (dl ^ kswz)];
      kb[0]      = (u16)k01;
      kb[LP]     = (u16)(k01 >> 16);
      kb[2 * LP] = (u16)k23;
      kb[3 * LP] = (u16)(k23 >> 16);
      u16* vb = &vls[dl * LP + vpb];
      vb[0]  = (u16)v01;
      vb[4]  = (u16)(v01 >> 16);
      vb[8]  = (u16)v23;
      vb[12] = (u16)(v23 >> 16);
    }
    int sk[4];
#pragma unroll
    for (int n4 = 0; n4 < 4; ++n4) sk[n4] = segb[s0 + n4 * 16 + l16];
    __syncthreads();                     // staging visible

    // ---- S = Q K^T, both streams (B-frag: n=key=n4*16+l16, k=d) -----------
    f32x4 S0[4], Sb[4];
#pragma unroll
    for (int n4 = 0; n4 < 4; ++n4) {
      const int scol = n4 * 16 + l16;
      const int h8   = ((scol >> 2) & 7) << 3;         // read-side unswizzle
      f32x4 a0 = {0.f, 0.f, 0.f, 0.f}, ab = {0.f, 0.f, 0.f, 0.f};
#pragma unroll
      for (int kc = 0; kc < 2; ++kc) {
        bf16x8 kf = *(const bf16x8*)&ktr[scol * LP + ((kc * 32 + quad * 8) ^ h8)];
        a0 = __builtin_amdgcn_mfma_f32_16x16x32_bf16(q0f[kc].v, kf, a0, 0, 0, 0);
        ab = __builtin_amdgcn_mfma_f32_16x16x32_bf16(qbf[kc].v, kf, ab, 0, 0, 0);
      }
      S0[n4] = a0; Sb[n4] = ab;
    }

    // ---- no-max softmax: raw exp2, per-lane partial row sums --------------
#pragma unroll
    for (int r = 0; r < 4; ++r) {
      float p0[4], pb[4];
#pragma unroll
      for (int n4 = 0; n4 < 4; ++n4) {
        p0[n4] = fexp2(S0[n4][r]);
        pb[n4] = (sk[n4] == sq[r]) ? fexp2(Sb[n4][r]) : 0.f;
      }
      rs0[r] += (p0[0] + p0[1]) + (p0[2] + p0[3]);
      rsb[r] += (pb[0] + pb[1]) + (pb[2] + pb[3]);
      // P at col' = l16*4 + n4  (matches V's perm)  -> one b64 per stream
      *(uint2*)&Pw[(quad * 4 + r) * LP + l16 * 4] =
          make_uint2(pkbf(p0[0], p0[1]), pkbf(p0[2], p0[3]));
      *(uint2*)&Pw[16 * LP + (quad * 4 + r) * LP + l16 * 4] =
          make_uint2(pkbf(pb[0], pb[1]), pkbf(pb[2], pb[3]));
    }
    asm volatile("s_waitcnt lgkmcnt(0)" ::: "memory");  // wave-private P RAW

    // ---- O += P V  (A=P[m=q][k=col'], B=V[k=col'][n=d]) -------------------
#pragma unroll
    for (int kc = 0; kc < 2; ++kc) {
      bf16x8 pf0 = *(const bf16x8*)&Pw[l16 * LP + kc * 32 + quad * 8];
      bf16x8 pfb = *(const bf16x8*)&Pw[16 * LP + l16 * LP + kc * 32 + quad * 8];
#pragma unroll
      for (int dt = 0; dt < 4; ++dt) {
        bf16x8 vf = *(const bf16x8*)&vls[(dt * 16 + l16) * LP + kc * 32 + quad * 8];
        O0[dt] = __builtin_amdgcn_mfma_f32_16x16x32_bf16(pf0, vf, O0[dt], 0, 0, 0);
        Ob[dt] = __builtin_amdgcn_mfma_f32_16x16x32_bf16(pfb, vf, Ob[dt], 0, 0, 0);
      }
    }
  }

  // ---- final row-sum reduction (within 16-lane row groups) -----------------
#pragma unroll
  for (int r = 0; r < 4; ++r)
#pragma unroll
    for (int off = 1; off < 16; off <<= 1) {
      rs0[r] += __shfl_xor(rs0[r], off, 64);
      rsb[r] += __shfl_xor(rsb[r], off, 64);
    }
  float inv0[4], invb[4];
#pragma unroll
  for (int r = 0; r < 4; ++r) {
    inv0[r] = (rs0[r] > 0.f) ? 1.f / rs0[r] : 0.f;
    invb[r] = (rsb[r] > 0.f) ? 1.f / rsb[r] : 0.f;
  }

  // ---- epilogue: divide, add analytic v-biases, transpose via LDS, store ---
  __syncthreads();                        // all LDS tile reads done
  float* fbuf = (float*)smem;             // [64 d][65] fp32
  const float* tvn = tok + 8 * 192 + 128;
#pragma unroll
  for (int dt = 0; dt < 4; ++dt) {
    const int d = dt * 16 + l16;
    const float bn = tvn[d];
#pragma unroll
    for (int r = 0; r < 4; ++r) {
      float bc = tok[sq[r] * 192 + 128 + d];
      float vA = O0[dt][r] * inv0[r] + bn;
      float vB = Ob[dt][r] * invb[r] + bc;
      fbuf[d * 65 + wave * 16 + quad * 4 + r] = 0.5f * (vA + vB);
    }
  }
  __syncthreads();
  {
    // out flat = d*65536 + bh*1024 + t   (stacked (ch, bH, T) row-major)
    const size_t obase = (size_t)bh * 1024 + qt * 64;
    for (int i = tid; i < 4096; i += 256) {
      int d = i >> 6, t = i & 63;
      out[(size_t)d * 65536 + obase + t] = fbuf[d * 65 + t];
    }
  }
}

// ---- host ------------------------------------------------------------------
extern "C" void kernel_launch(void* const* d_in, const int* in_sizes, int n_in,
                              void* d_out, int out_size, void* d_ws, size_t ws_size,
                              hipStream_t stream) {
  (void)in_sizes; (void)n_in; (void)out_size; (void)ws_size;
  const float* qkv   = (const float*)d_in[0];
  const int*   amask = (const int*)d_in[1];
  const float* emb   = (const float*)d_in[2];
  const float* wcls  = (const float*)d_in[3];
  float* tok = (float*)d_ws;
  float* out = (float*)d_out;

  hipLaunchKernelGGL(tok_kernel, dim3(9), dim3(192), 0, stream, wcls, emb, tok);
  hipLaunchKernelGGL(attn_kernel, dim3(64, 16), dim3(256), 0, stream,
                     qkv, amask, tok, out);
}

// Round 8
// 176.126 us; speedup vs baseline: 1.8130x; 1.0083x over previous
//
#include <hip/hip_runtime.h>
#include <stdint.h>

typedef unsigned short u16;
typedef unsigned int   u32;
typedef __bf16 bf16_t;
typedef bf16_t bf16x8 __attribute__((ext_vector_type(8)));
typedef bf16_t bf16x2 __attribute__((ext_vector_type(2)));
typedef float  f32x2  __attribute__((ext_vector_type(2)));
typedef float  f32x4  __attribute__((ext_vector_type(4)));

// bs=8, H=8 -> bH=64 ; T=1024 ; ch=64 ; classes 0..7, null token idx 8.
// Math: k-bias is row-constant over surviving keys -> drops out of softmax;
// v-bias passes through softmax as exactly +v_bias -> added in epilogue;
// counter==2 -> out = 0.5*(A_null + A_class).  No-max softmax: logits in
// exp2-domain have sigma~1.44 (scale folded into Q), so raw exp2 is safe.
//
// Lessons: R5/R6 -- register prefetch beyond the 64-VGPR allocation spills to
// scratch (429 MB/dispatch, 2.2x slower); waves_per_eu didn't lift the budget.
// R7 -- raw v_exp_f32 cut VALUBusy 39->27%.  R8 -- blocks re-read K/V 16x;
// grid(64,16) scatters same-bh blocks over all XCDs so reuse is served by L3
// (~557 MB @ ~6 TB/s = the 93 us wall).  XCD swizzle pins each bh's 16
// qt-blocks to ONE XCD: per-XCD K/V set = 8 bh x 512 KB = 4 MB = its L2.
#define QSCALE 0.18033688011112042f   /* 0.125 * log2(e) */
#define LP 72                          /* LDS pitch (elems) for ktr/vls/P */

__device__ __forceinline__ u32 pkbf(float a, float b) {
  f32x2 x = {a, b};
  bf16x2 y = __builtin_convertvector(x, bf16x2);   // RNE; v_cvt_pk_bf16_f32
  union { bf16x2 v; u32 u; } c; c.v = y; return c.u;
}

// raw v_exp_f32: libm exp2f (no fast-math) lowers to a multi-instruction
// denormal-fixup expansion; raw instruction is exact for our exponent range.
__device__ __forceinline__ float fexp2(float x) {
#if __has_builtin(__builtin_amdgcn_exp2f)
  return __builtin_amdgcn_exp2f(x);
#else
  float r;
  asm("v_exp_f32 %0, %1\n\ts_nop 0" : "=v"(r) : "v"(x));
  return r;
#endif
}

// ---- kernel 1: tok[c][j] = sum_i W_cls[j,i] * embed[c,i]  (9 x 192) --------
__global__ void tok_kernel(const float* __restrict__ W, const float* __restrict__ E,
                           float* __restrict__ tok) {
  int c = blockIdx.x;           // 0..8
  int j = threadIdx.x;          // 0..191
  const f32x4* wr = (const f32x4*)(W + j * 512);
  const f32x4* er = (const f32x4*)(E + c * 512);
  float acc = 0.f;
  for (int i = 0; i < 128; ++i) {
    f32x4 w = wr[i], e = er[i];
    acc += w.x * e.x + w.y * e.y + w.z * e.z + w.w * e.w;
  }
  tok[c * 192 + j] = acc;
}

// ---- kernel 2: two-stream flash attention ----------------------------------
__global__ __launch_bounds__(256, 4)
void attn_kernel(const float* __restrict__ qkv, const int* __restrict__ seg,
                 const float* __restrict__ tok, float* __restrict__ out) {
  // ktr [64 s][LP] (K transposed, columns XOR-swizzled) | vls [64 d][LP]
  // (V, key order permuted: col' = (s&15)*4 + (s>>4)) | P per wave [2][16][LP]
  __shared__ __align__(16) u16 smem[64 * LP * 2 + 4 * 2 * 16 * LP];  // 36864 B
  u16* ktr = smem;
  u16* vls = smem + 64 * LP;

  // XCD-aware decode: whole grid (1024 blocks) is co-resident (4 blocks/CU);
  // blocks are assigned to XCDs round-robin on linear id, so L&7 = XCD.
  // All 16 qt-blocks of a bh land on one XCD -> K/V reuse served by its L2.
  const int L  = blockIdx.x;
  const int bh = (L & 7) * 8 + ((L >> 3) & 7);   // 0..63
  const int qt = L >> 6;                          // 0..15
  const int b  = bh >> 3;
  const int tid = threadIdx.x, wave = tid >> 6, lane = tid & 63;
  const int quad = lane >> 4, l16 = lane & 15;
  u16* Pw = smem + 2 * 64 * LP + wave * (2 * 16 * LP);

  const float* qg   = qkv + (size_t)bh * 192 * 1024;   // head slab [192][1024]
  const int*   segb = seg + b * 1024;

  // --- per-lane segment info -------------------------------------------------
  const int tq = qt * 64 + wave * 16 + l16;
  const int mycls = segb[tq];
  int sq[4];
#pragma unroll
  for (int r = 0; r < 4; ++r) sq[r] = segb[qt * 64 + wave * 16 + quad * 4 + r];

  // --- Q fragments (A-layout: m=l16=query, k=d=kc*32+quad*8+j) --------------
  const float* tn = tok + 8 * 192;
  const float* tc = tok + mycls * 192;
  union { u32 w[4]; bf16x8 v; } q0f[2], qbf[2];
#pragma unroll
  for (int kc = 0; kc < 2; ++kc)
#pragma unroll
    for (int jj = 0; jj < 4; ++jj) {
      int d = kc * 32 + quad * 8 + jj * 2;
      float a0 = qg[(size_t)d * 1024 + tq];
      float a1 = qg[(size_t)(d + 1) * 1024 + tq];
      q0f[kc].w[jj] = pkbf((a0 + tn[d]) * QSCALE, (a1 + tn[d + 1]) * QSCALE);
      qbf[kc].w[jj] = pkbf((a0 + tc[d]) * QSCALE, (a1 + tc[d + 1]) * QSCALE);
    }

  f32x4 O0[4], Ob[4];
#pragma unroll
  for (int dt = 0; dt < 4; ++dt) {
    O0[dt] = (f32x4){0.f, 0.f, 0.f, 0.f};
    Ob[dt] = (f32x4){0.f, 0.f, 0.f, 0.f};
  }
  float rs0[4] = {0.f, 0.f, 0.f, 0.f}, rsb[4] = {0.f, 0.f, 0.f, 0.f};

  // --- staging thread constants ---------------------------------------------
  const int c4 = tid & 15, row0 = tid >> 4;            // float4 col, d-row base
  const f32x4* kg4 = (const f32x4*)(qg + 64 * 1024);
  const f32x4* vg4 = (const f32x4*)(qg + 128 * 1024);
  const int vpb   = 16 * (c4 & 3) + (c4 >> 2);         // perm(4*c4+i) = vpb+4i
  const int kswz  = (c4 & 7) << 3;                     // ktr column XOR swizzle

  // ---- key-tile loop (16 x 64 keys) ----------------------------------------
  for (int kt = 0; kt < 16; ++kt) {
    const int s0 = kt * 64;
    __syncthreads();                     // prior tile's LDS reads complete

    // stage K (transposed+swizzled) and V (permuted cols) -------------------
#pragma unroll
    for (int r2 = 0; r2 < 4; ++r2) {
      const int dl = r2 * 16 + row0;
      f32x4 kv = kg4[dl * 256 + kt * 16 + c4];
      f32x4 vv = vg4[dl * 256 + kt * 16 + c4];
      u32 k01 = pkbf(kv.x, kv.y), k23 = pkbf(kv.z, kv.w);
      u32 v01 = pkbf(vv.x, vv.y), v23 = pkbf(vv.z, vv.w);
      u16* kb = &ktr[(4 * c4) * LP + (dl ^ kswz)];
      kb[0]      = (u16)k01;
      kb[LP]     = (u16)(k01 >> 16);
      kb[2 * LP] = (u16)k23;
      kb[3 * LP] = (u16)(k23 >> 16);
      u16* vb = &vls[dl * LP + vpb];
      vb[0]  = (u16)v01;
      vb[4]  = (u16)(v01 >> 16);
      vb[8]  = (u16)v23;
      vb[12] = (u16)(v23 >> 16);
    }
    int sk[4];
#pragma unroll
    for (int n4 = 0; n4 < 4; ++n4) sk[n4] = segb[s0 + n4 * 16 + l16];
    __syncthreads();                     // staging visible

    // ---- S = Q K^T, both streams (B-frag: n=key=n4*16+l16, k=d) -----------
    f32x4 S0[4], Sb[4];
#pragma unroll
    for (int n4 = 0; n4 < 4; ++n4) {
      const int scol = n4 * 16 + l16;
      const int h8   = ((scol >> 2) & 7) << 3;         // read-side unswizzle
      f32x4 a0 = {0.f, 0.f, 0.f, 0.f}, ab = {0.f, 0.f, 0.f, 0.f};
#pragma unroll
      for (int kc = 0; kc < 2; ++kc) {
        bf16x8 kf = *(const bf16x8*)&ktr[scol * LP + ((kc * 32 + quad * 8) ^ h8)];
        a0 = __builtin_amdgcn_mfma_f32_16x16x32_bf16(q0f[kc].v, kf, a0, 0, 0, 0);
        ab = __builtin_amdgcn_mfma_f32_16x16x32_bf16(qbf[kc].v, kf, ab, 0, 0, 0);
      }
      S0[n4] = a0; Sb[n4] = ab;
    }

    // ---- no-max softmax: raw exp2, per-lane partial row sums --------------
#pragma unroll
    for (int r = 0; r < 4; ++r) {
      float p0[4], pb[4];
#pragma unroll
      for (int n4 = 0; n4 < 4; ++n4) {
        p0[n4] = fexp2(S0[n4][r]);
        pb[n4] = (sk[n4] == sq[r]) ? fexp2(Sb[n4][r]) : 0.f;
      }
      rs0[r] += (p0[0] + p0[1]) + (p0[2] + p0[3]);
      rsb[r] += (pb[0] + pb[1]) + (pb[2] + pb[3]);
      // P at col' = l16*4 + n4  (matches V's perm)  -> one b64 per stream
      *(uint2*)&Pw[(quad * 4 + r) * LP + l16 * 4] =
          make_uint2(pkbf(p0[0], p0[1]), pkbf(p0[2], p0[3]));
      *(uint2*)&Pw[16 * LP + (quad * 4 + r) * LP + l16 * 4] =
          make_uint2(pkbf(pb[0], pb[1]), pkbf(pb[2], pb[3]));
    }
    asm volatile("s_waitcnt lgkmcnt(0)" ::: "memory");  // wave-private P RAW

    // ---- O += P V  (A=P[m=q][k=col'], B=V[k=col'][n=d]) -------------------
#pragma unroll
    for (int kc = 0; kc < 2; ++kc) {
      bf16x8 pf0 = *(const bf16x8*)&Pw[l16 * LP + kc * 32 + quad * 8];
      bf16x8 pfb = *(const bf16x8*)&Pw[16 * LP + l16 * LP + kc * 32 + quad * 8];
#pragma unroll
      for (int dt = 0; dt < 4; ++dt) {
        bf16x8 vf = *(const bf16x8*)&vls[(dt * 16 + l16) * LP + kc * 32 + quad * 8];
        O0[dt] = __builtin_amdgcn_mfma_f32_16x16x32_bf16(pf0, vf, O0[dt], 0, 0, 0);
        Ob[dt] = __builtin_amdgcn_mfma_f32_16x16x32_bf16(pfb, vf, Ob[dt], 0, 0, 0);
      }
    }
  }

  // ---- final row-sum reduction (within 16-lane row groups) -----------------
#pragma unroll
  for (int r = 0; r < 4; ++r)
#pragma unroll
    for (int off = 1; off < 16; off <<= 1) {
      rs0[r] += __shfl_xor(rs0[r], off, 64);
      rsb[r] += __shfl_xor(rsb[r], off, 64);
    }
  float inv0[4], invb[4];
#pragma unroll
  for (int r = 0; r < 4; ++r) {
    inv0[r] = (rs0[r] > 0.f) ? 1.f / rs0[r] : 0.f;
    invb[r] = (rsb[r] > 0.f) ? 1.f / rsb[r] : 0.f;
  }

  // ---- epilogue: divide, add analytic v-biases, transpose via LDS, store ---
  __syncthreads();                        // all LDS tile reads done
  float* fbuf = (float*)smem;             // [64 d][65] fp32
  const float* tvn = tok + 8 * 192 + 128;
#pragma unroll
  for (int dt = 0; dt < 4; ++dt) {
    const int d = dt * 16 + l16;
    const float bn = tvn[d];
#pragma unroll
    for (int r = 0; r < 4; ++r) {
      float bc = tok[sq[r] * 192 + 128 + d];
      float vA = O0[dt][r] * inv0[r] + bn;
      float vB = Ob[dt][r] * invb[r] + bc;
      fbuf[d * 65 + wave * 16 + quad * 4 + r] = 0.5f * (vA + vB);
    }
  }
  __syncthreads();
  {
    // out flat = d*65536 + bh*1024 + t   (stacked (ch, bH, T) row-major)
    const size_t obase = (size_t)bh * 1024 + qt * 64;
    for (int i = tid; i < 4096; i += 256) {
      int d = i >> 6, t = i & 63;
      out[(size_t)d * 65536 + obase + t] = fbuf[d * 65 + t];
    }
  }
}

// ---- host ------------------------------------------------------------------
extern "C" void kernel_launch(void* const* d_in, const int* in_sizes, int n_in,
                              void* d_out, int out_size, void* d_ws, size_t ws_size,
                              hipStream_t stream) {
  (void)in_sizes; (void)n_in; (void)out_size; (void)ws_size;
  const float* qkv   = (const float*)d_in[0];
  const int*   amask = (const int*)d_in[1];
  const float* emb   = (const float*)d_in[2];
  const float* wcls  = (const float*)d_in[3];
  float* tok = (float*)d_ws;
  float* out = (float*)d_out;

  hipLaunchKernelGGL(tok_kernel, dim3(9), dim3(192), 0, stream, wcls, emb, tok);
  hipLaunchKernelGGL(attn_kernel, dim3(1024), dim3(256), 0, stream,
                     qkv, amask, tok, out);
}

// Round 9
// 145.598 us; speedup vs baseline: 2.1931x; 1.2097x over previous
//
#include <hip/hip_runtime.h>
#include <stdint.h>

typedef unsigned short u16;
typedef unsigned int   u32;
typedef __bf16 bf16_t;
typedef bf16_t bf16x8 __attribute__((ext_vector_type(8)));
typedef bf16_t bf16x2 __attribute__((ext_vector_type(2)));
typedef float  f32x2  __attribute__((ext_vector_type(2)));
typedef float  f32x4  __attribute__((ext_vector_type(4)));

// bs=8, H=8 -> bH=64 ; T=1024 ; ch=64 ; classes 0..7, null token idx 8.
// Math: k-bias is row-constant over surviving keys -> drops out of softmax;
// v-bias passes through softmax as exactly +v_bias -> added in epilogue;
// counter==2 -> out = 0.5*(A_null + A_class).  No-max softmax: logits in
// exp2-domain have sigma~1.44 (scale folded into Q), so raw exp2 is safe.
//
// Lessons: R5/R6 -- register prefetch beyond the 64-VGPR allocation spills
// (429 MB scratch writes, 2.2x); waves_per_eu didn't lift the budget.
// R7 -- raw v_exp_f32 cut VALUBusy 39->27%.  R8 -- XCD swizzle: zero effect;
// not L3-bound.  R9 theory: LDS pipe is the wall (~60 LDS instr/wave-tile,
// 32 of them scalar b16 writes + 7.5M conflict cycles ~= 56 of 93 us).
// This round: K staged via d-strided coalesced loads -> 2x ds_write_b128;
// V via sigma-grouped loads -> 4x ds_write_b64; no swizzle needed (LP=72
// rows = 9 chunks of 16B -> natural conflict-free chunk mapping).
#define QSCALE 0.18033688011112042f   /* 0.125 * log2(e) */
#define LP 72                          /* LDS pitch (elems) for ktr/vls/P */

__device__ __forceinline__ u32 pkbf(float a, float b) {
  f32x2 x = {a, b};
  bf16x2 y = __builtin_convertvector(x, bf16x2);   // RNE; v_cvt_pk_bf16_f32
  union { bf16x2 v; u32 u; } c; c.v = y; return c.u;
}

// raw v_exp_f32: libm exp2f (no fast-math) lowers to a multi-instruction
// denormal-fixup expansion; raw instruction is exact for our exponent range.
__device__ __forceinline__ float fexp2(float x) {
#if __has_builtin(__builtin_amdgcn_exp2f)
  return __builtin_amdgcn_exp2f(x);
#else
  float r;
  asm("v_exp_f32 %0, %1\n\ts_nop 0" : "=v"(r) : "v"(x));
  return r;
#endif
}

// ---- kernel 1: tok[c][j] = sum_i W_cls[j,i] * embed[c,i]  (9 x 192) --------
__global__ void tok_kernel(const float* __restrict__ W, const float* __restrict__ E,
                           float* __restrict__ tok) {
  int c = blockIdx.x;           // 0..8
  int j = threadIdx.x;          // 0..191
  const f32x4* wr = (const f32x4*)(W + j * 512);
  const f32x4* er = (const f32x4*)(E + c * 512);
  float acc = 0.f;
  for (int i = 0; i < 128; ++i) {
    f32x4 w = wr[i], e = er[i];
    acc += w.x * e.x + w.y * e.y + w.z * e.z + w.w * e.w;
  }
  tok[c * 192 + j] = acc;
}

// ---- kernel 2: two-stream flash attention ----------------------------------
__global__ __launch_bounds__(256, 4)
void attn_kernel(const float* __restrict__ qkv, const int* __restrict__ seg,
                 const float* __restrict__ tok, float* __restrict__ out) {
  // ktr [64 s][LP] (K transposed [s][d], no swizzle) | vls [64 d][LP]
  // (V, key order sigma(s) = (s&15)*4 + (s>>4))      | P per wave [2][16][LP]
  __shared__ __align__(16) u16 smem[64 * LP * 2 + 4 * 2 * 16 * LP];  // 36864 B
  u16* ktr = smem;
  u16* vls = smem + 64 * LP;

  const int L  = blockIdx.x;
  const int bh = (L & 7) * 8 + ((L >> 3) & 7);   // 0..63
  const int qt = L >> 6;                          // 0..15
  const int b  = bh >> 3;
  const int tid = threadIdx.x, wave = tid >> 6, lane = tid & 63;
  const int quad = lane >> 4, l16 = lane & 15;
  u16* Pw = smem + 2 * 64 * LP + wave * (2 * 16 * LP);

  const float* qg   = qkv + (size_t)bh * 192 * 1024;   // head slab [192][1024]
  const int*   segb = seg + b * 1024;

  // --- per-lane segment info -------------------------------------------------
  const int tq = qt * 64 + wave * 16 + l16;
  const int mycls = segb[tq];
  int sq[4];
#pragma unroll
  for (int r = 0; r < 4; ++r) sq[r] = segb[qt * 64 + wave * 16 + quad * 4 + r];

  // --- Q fragments (A-layout: m=l16=query, k=d=kc*32+quad*8+j) --------------
  const float* tn = tok + 8 * 192;
  const float* tc = tok + mycls * 192;
  union { u32 w[4]; bf16x8 v; } q0f[2], qbf[2];
#pragma unroll
  for (int kc = 0; kc < 2; ++kc)
#pragma unroll
    for (int jj = 0; jj < 4; ++jj) {
      int d = kc * 32 + quad * 8 + jj * 2;
      float a0 = qg[(size_t)d * 1024 + tq];
      float a1 = qg[(size_t)(d + 1) * 1024 + tq];
      q0f[kc].w[jj] = pkbf((a0 + tn[d]) * QSCALE, (a1 + tn[d + 1]) * QSCALE);
      qbf[kc].w[jj] = pkbf((a0 + tc[d]) * QSCALE, (a1 + tc[d + 1]) * QSCALE);
    }

  f32x4 O0[4], Ob[4];
#pragma unroll
  for (int dt = 0; dt < 4; ++dt) {
    O0[dt] = (f32x4){0.f, 0.f, 0.f, 0.f};
    Ob[dt] = (f32x4){0.f, 0.f, 0.f, 0.f};
  }
  float rs0[4] = {0.f, 0.f, 0.f, 0.f}, rsb[4] = {0.f, 0.f, 0.f, 0.f};

  // --- staging thread constants ---------------------------------------------
  const int sK = tid & 63, gK = tid >> 6;   // K: key s, d-group (16 d's)
  const int lV = tid & 15, dgV = tid >> 4;  // V: sigma col l, d-group (4 d's)
  const float* kbase = qg + (size_t)(64  + gK * 16) * 1024 + sK;
  const float* vbase = qg + (size_t)(128 + dgV * 4) * 1024 + lV;

  // ---- key-tile loop (16 x 64 keys) ----------------------------------------
  for (int kt = 0; kt < 16; ++kt) {
    const int s0 = kt * 64;
    __syncthreads();                     // prior tile's LDS reads complete

    // K: 16 d-strided coalesced dword loads for this thread's key column s
    float kf[16];
#pragma unroll
    for (int i = 0; i < 16; ++i) kf[i] = kbase[(size_t)i * 1024 + s0];
    // V: 4 d-rows x 4 sigma-grouped s positions {l, l+16, l+32, l+48}
    float vf[4][4];
#pragma unroll
    for (int i = 0; i < 4; ++i)
#pragma unroll
      for (int m = 0; m < 4; ++m) vf[i][m] = vbase[(size_t)i * 1024 + s0 + m * 16];

    // K -> ktr[s][d]: two b128 writes (conflict-free: chunk = 9s+g mod 8)
    {
      u32 kp[8];
#pragma unroll
      for (int j = 0; j < 8; ++j) kp[j] = pkbf(kf[2 * j], kf[2 * j + 1]);
      *(uint4*)&ktr[sK * LP + gK * 16]     = make_uint4(kp[0], kp[1], kp[2], kp[3]);
      *(uint4*)&ktr[sK * LP + gK * 16 + 8] = make_uint4(kp[4], kp[5], kp[6], kp[7]);
    }
    // V -> vls[d][sigma(s)]: one b64 per d (sigma(l+16m) = l*4+m, contiguous)
#pragma unroll
    for (int i = 0; i < 4; ++i)
      *(uint2*)&vls[(dgV * 4 + i) * LP + lV * 4] =
          make_uint2(pkbf(vf[i][0], vf[i][1]), pkbf(vf[i][2], vf[i][3]));

    int sk[4];
#pragma unroll
    for (int n4 = 0; n4 < 4; ++n4) sk[n4] = segb[s0 + n4 * 16 + l16];
    __syncthreads();                     // staging visible

    // ---- S = Q K^T, both streams (B-frag: n=key=n4*16+l16, k=d) -----------
    f32x4 S0[4], Sb[4];
#pragma unroll
    for (int n4 = 0; n4 < 4; ++n4) {
      const int scol = n4 * 16 + l16;
      f32x4 a0 = {0.f, 0.f, 0.f, 0.f}, ab = {0.f, 0.f, 0.f, 0.f};
#pragma unroll
      for (int kc = 0; kc < 2; ++kc) {
        bf16x8 kfr = *(const bf16x8*)&ktr[scol * LP + kc * 32 + quad * 8];
        a0 = __builtin_amdgcn_mfma_f32_16x16x32_bf16(q0f[kc].v, kfr, a0, 0, 0, 0);
        ab = __builtin_amdgcn_mfma_f32_16x16x32_bf16(qbf[kc].v, kfr, ab, 0, 0, 0);
      }
      S0[n4] = a0; Sb[n4] = ab;
    }

    // ---- no-max softmax: raw exp2, per-lane partial row sums --------------
#pragma unroll
    for (int r = 0; r < 4; ++r) {
      float p0[4], pb[4];
#pragma unroll
      for (int n4 = 0; n4 < 4; ++n4) {
        p0[n4] = fexp2(S0[n4][r]);
        pb[n4] = (sk[n4] == sq[r]) ? fexp2(Sb[n4][r]) : 0.f;
      }
      rs0[r] += (p0[0] + p0[1]) + (p0[2] + p0[3]);
      rsb[r] += (pb[0] + pb[1]) + (pb[2] + pb[3]);
      // P at col' = sigma(s) = l16*4 + n4  -> one b64 per stream
      *(uint2*)&Pw[(quad * 4 + r) * LP + l16 * 4] =
          make_uint2(pkbf(p0[0], p0[1]), pkbf(p0[2], p0[3]));
      *(uint2*)&Pw[16 * LP + (quad * 4 + r) * LP + l16 * 4] =
          make_uint2(pkbf(pb[0], pb[1]), pkbf(pb[2], pb[3]));
    }
    asm volatile("s_waitcnt lgkmcnt(0)" ::: "memory");  // wave-private P RAW

    // ---- O += P V  (A=P[m=q][k=col'], B=V[k=col'][n=d]) -------------------
#pragma unroll
    for (int kc = 0; kc < 2; ++kc) {
      bf16x8 pf0 = *(const bf16x8*)&Pw[l16 * LP + kc * 32 + quad * 8];
      bf16x8 pfb = *(const bf16x8*)&Pw[16 * LP + l16 * LP + kc * 32 + quad * 8];
#pragma unroll
      for (int dt = 0; dt < 4; ++dt) {
        bf16x8 vfr = *(const bf16x8*)&vls[(dt * 16 + l16) * LP + kc * 32 + quad * 8];
        O0[dt] = __builtin_amdgcn_mfma_f32_16x16x32_bf16(pf0, vfr, O0[dt], 0, 0, 0);
        Ob[dt] = __builtin_amdgcn_mfma_f32_16x16x32_bf16(pfb, vfr, Ob[dt], 0, 0, 0);
      }
    }
  }

  // ---- final row-sum reduction (within 16-lane row groups) -----------------
#pragma unroll
  for (int r = 0; r < 4; ++r)
#pragma unroll
    for (int off = 1; off < 16; off <<= 1) {
      rs0[r] += __shfl_xor(rs0[r], off, 64);
      rsb[r] += __shfl_xor(rsb[r], off, 64);
    }
  float inv0[4], invb[4];
#pragma unroll
  for (int r = 0; r < 4; ++r) {
    inv0[r] = (rs0[r] > 0.f) ? 1.f / rs0[r] : 0.f;
    invb[r] = (rsb[r] > 0.f) ? 1.f / rsb[r] : 0.f;
  }

  // ---- epilogue: divide, add analytic v-biases, transpose via LDS, store ---
  __syncthreads();                        // all LDS tile reads done
  float* fbuf = (float*)smem;             // [64 d][65] fp32
  const float* tvn = tok + 8 * 192 + 128;
#pragma unroll
  for (int dt = 0; dt < 4; ++dt) {
    const int d = dt * 16 + l16;
    const float bn = tvn[d];
#pragma unroll
    for (int r = 0; r < 4; ++r) {
      float bc = tok[sq[r] * 192 + 128 + d];
      float vA = O0[dt][r] * inv0[r] + bn;
      float vB = Ob[dt][r] * invb[r] + bc;
      fbuf[d * 65 + wave * 16 + quad * 4 + r] = 0.5f * (vA + vB);
    }
  }
  __syncthreads();
  {
    // out flat = d*65536 + bh*1024 + t   (stacked (ch, bH, T) row-major)
    const size_t obase = (size_t)bh * 1024 + qt * 64;
    for (int i = tid; i < 4096; i += 256) {
      int d = i >> 6, t = i & 63;
      out[(size_t)d * 65536 + obase + t] = fbuf[d * 65 + t];
    }
  }
}

// ---- host ------------------------------------------------------------------
extern "C" void kernel_launch(void* const* d_in, const int* in_sizes, int n_in,
                              void* d_out, int out_size, void* d_ws, size_t ws_size,
                              hipStream_t stream) {
  (void)in_sizes; (void)n_in; (void)out_size; (void)ws_size;
  const float* qkv   = (const float*)d_in[0];
  const int*   amask = (const int*)d_in[1];
  const float* emb   = (const float*)d_in[2];
  const float* wcls  = (const float*)d_in[3];
  float* tok = (float*)d_ws;
  float* out = (float*)d_out;

  hipLaunchKernelGGL(tok_kernel, dim3(9), dim3(192), 0, stream, wcls, emb, tok);
  hipLaunchKernelGGL(attn_kernel, dim3(1024), dim3(256), 0, stream,
                     qkv, amask, tok, out);
}